// Round 4
// baseline (277.755 us; speedup 1.0000x reference)
//
#include <hip/hip_runtime.h>
#include <hip/hip_bf16.h>

typedef __attribute__((ext_vector_type(8))) short short8;
typedef __attribute__((ext_vector_type(4))) float floatx4;

__device__ inline unsigned short f2bf(float f) {
    unsigned u = __float_as_uint(f);
    u += 0x7fffu + ((u >> 16) & 1u);   // round-to-nearest-even
    return (unsigned short)(u >> 16);
}

// ---------------- prep: weights->bf16, fused biases, zero CSR counters ----------------

__global__ void prep_weights(const float* __restrict__ w_in, const float* __restrict__ w1s,
                             const float* __restrict__ w1n, const float* __restrict__ w2s,
                             const float* __restrict__ w2n,
                             const float* __restrict__ b_in, const float* __restrict__ b1s,
                             const float* __restrict__ b1n, const float* __restrict__ b2s,
                             const float* __restrict__ b2n,
                             unsigned short* __restrict__ wb, float* __restrict__ biasf,
                             int* __restrict__ chunk_count, int* __restrict__ done_ctr) {
    int idx = blockIdx.x * 256 + threadIdx.x;
    if (idx < 5 * 16384) {
        int m = idx >> 14, j = idx & 16383;
        const float* src = (m == 0) ? w_in : (m == 1) ? w1s : (m == 2) ? w1n : (m == 3) ? w2s : w2n;
        wb[idx] = f2bf(src[j]);
    }
    if (idx < 128) {
        biasf[idx]       = b_in[idx];
        biasf[128 + idx] = b1s[idx] + b1n[idx];
        biasf[256 + idx] = b2s[idx] + b2n[idx];
    }
    if (blockIdx.x == 0) {
        if (threadIdx.x < 128) chunk_count[threadIdx.x] = 0;
        if (threadIdx.x == 128) *done_ctr = 0;
    }
}

// ---------------- CSR build: binned counting sort (coalesced writes) ----------------
// chunk = 512 consecutive target nodes; NCHUNK <= 128.
// packed edge word: (chunk<<25) | (src<<9) | (tgt&511)   [requires src < 65536]

__global__ __launch_bounds__(256) void chunk_hist(const int* __restrict__ e,
                                                  int* __restrict__ chunk_count,
                                                  int* __restrict__ chunk_base,
                                                  int* __restrict__ chunk_cursor,
                                                  int* __restrict__ done_ctr,
                                                  int E, int nblocks) {
    __shared__ int h[128];
    __shared__ int lastf;
    int t = threadIdx.x;
    if (t < 128) h[t] = 0;
    __syncthreads();
    for (int i = blockIdx.x * 256 + t; i < E; i += nblocks * 256)
        atomicAdd(&h[e[E + i] >> 9], 1);
    __syncthreads();
    if (t < 128 && h[t]) atomicAdd(&chunk_count[t], h[t]);
    __threadfence();
    if (t == 0) lastf = (atomicAdd(done_ctr, 1) == nblocks - 1);
    __syncthreads();
    if (lastf) {
        // last finishing block performs the 128-wide exclusive scan
        int cv = (t < 128) ? atomicAdd(&chunk_count[t], 0) : 0;  // coherent read
        if (t < 128) h[t] = cv;
        __syncthreads();
        for (int o = 1; o < 128; o <<= 1) {
            int v = (t < 128 && t >= o) ? h[t - o] : 0;
            __syncthreads();
            if (t < 128) h[t] += v;
            __syncthreads();
        }
        if (t < 128) {
            int excl = h[t] - cv;
            chunk_base[t] = excl;
            chunk_cursor[t] = excl;
        }
    }
}

#define BTILE 4096

__global__ __launch_bounds__(256) void bin_pass(const int* __restrict__ e,
                                                int* __restrict__ chunk_cursor,
                                                unsigned* __restrict__ packed_out,
                                                int E, int ntiles) {
    __shared__ unsigned buf[BTILE];
    __shared__ unsigned sbuf[BTILE];
    __shared__ int hist[128], offs[128], gbase[128], lcur[128];
    int t = threadIdx.x;
    for (int tile = blockIdx.x; tile < ntiles; tile += gridDim.x) {
        int e0 = tile * BTILE;
        int cnt = min(BTILE, E - e0);
        if (t < 128) hist[t] = 0;
        __syncthreads();
        for (int j = t; j < cnt; j += 256) {
            unsigned src = (unsigned)e[e0 + j];
            unsigned tgt = (unsigned)e[E + e0 + j];
            unsigned c = tgt >> 9;
            buf[j] = (c << 25) | (src << 9) | (tgt & 511u);
            atomicAdd(&hist[c], 1);
        }
        __syncthreads();
        if (t < 128) offs[t] = hist[t];
        __syncthreads();
        for (int o = 1; o < 128; o <<= 1) {
            int v = (t < 128 && t >= o) ? offs[t - o] : 0;
            __syncthreads();
            if (t < 128) offs[t] += v;
            __syncthreads();
        }
        if (t < 128) {
            int excl = offs[t] - hist[t];
            offs[t] = excl;
            lcur[t] = excl;
            gbase[t] = (hist[t] > 0) ? atomicAdd(&chunk_cursor[t], hist[t]) : 0;
        }
        __syncthreads();
        for (int j = t; j < cnt; j += 256) {
            unsigned v = buf[j];
            int c = v >> 25;
            int p = atomicAdd(&lcur[c], 1);
            sbuf[p] = v;
        }
        __syncthreads();
        int wv = t >> 6, lane = t & 63;
        for (int c = wv; c < 128; c += 4) {
            int n = hist[c], lo = offs[c], gb = gbase[c];
            for (int j = lane; j < n; j += 64)
                packed_out[gb + j] = sbuf[lo + j];
        }
        __syncthreads();
    }
}

#define CSR_CAP 12288

__global__ __launch_bounds__(256) void chunk_csr(const unsigned* __restrict__ packed,
                                                 const int* __restrict__ chunk_base,
                                                 const int* __restrict__ chunk_cursor,
                                                 int* __restrict__ rows, int* __restrict__ colv,
                                                 int N) {
    __shared__ int hist[512], offs[512], lcnt[512], pp[256];
    __shared__ int sbuf[CSR_CAP];
    int c = blockIdx.x;
    int base = chunk_base[c];
    int cnt = chunk_cursor[c] - base;
    int t = threadIdx.x;
    hist[t] = 0;
    hist[t + 256] = 0;
    __syncthreads();
    for (int j = t; j < cnt; j += 256)
        atomicAdd(&hist[packed[base + j] & 511u], 1);
    __syncthreads();
    int a0 = hist[2 * t], a1 = hist[2 * t + 1];
    pp[t] = a0 + a1;
    __syncthreads();
    for (int o = 1; o < 256; o <<= 1) {
        int v = (t >= o) ? pp[t - o] : 0;
        __syncthreads();
        pp[t] += v;
        __syncthreads();
    }
    int excl = pp[t] - (a0 + a1);
    offs[2 * t] = excl;
    offs[2 * t + 1] = excl + a0;
    lcnt[2 * t] = 0;
    lcnt[2 * t + 1] = 0;
    __syncthreads();
    for (int j = t; j < 512; j += 256) {
        int node = c * 512 + j;
        if (node <= N) rows[node] = base + offs[j];
    }
    if (cnt <= CSR_CAP) {
        for (int j = t; j < cnt; j += 256) {
            unsigned v = packed[base + j];
            int node = v & 511u;
            int p = offs[node] + atomicAdd(&lcnt[node], 1);
            sbuf[p] = (v >> 9) & 0xFFFFu;
        }
        __syncthreads();
        for (int j = t; j < cnt; j += 256) colv[base + j] = sbuf[j];
    } else {
        for (int j = t; j < cnt; j += 256) {
            unsigned v = packed[base + j];
            int node = v & 511u;
            int p = offs[node] + atomicAdd(&lcnt[node], 1);
            colv[base + p] = (v >> 9) & 0xFFFFu;
        }
    }
}

// ---------------- segment mean (gather, one wave per node, 16-deep ILP) ----------------

__global__ __launch_bounds__(256) void agg_mean(const unsigned short* __restrict__ x,
                                                const int* __restrict__ rows,
                                                const int* __restrict__ colv,
                                                unsigned short* __restrict__ nm, int N) {
    int wid = (blockIdx.x * 256 + threadIdx.x) >> 6;
    int lane = threadIdx.x & 63;
    if (wid >= N) return;
    int s0 = rows[wid], s1 = rows[wid + 1];
    int deg = s1 - s0;
    int mn = deg < 64 ? deg : 64;
    int cvec = (lane < mn) ? colv[s0 + lane] : 0;
    float a0 = 0.f, a1 = 0.f;
    int lim = mn - 1;
    for (int j = 0; j < mn; j += 16) {
        unsigned v[16];
        #pragma unroll
        for (int u = 0; u < 16; ++u) {
            int idx = (j + u <= lim) ? (j + u) : lim;   // clamp: dup loads are cache hits
            int s = __shfl(cvec, idx, 64);
            v[u] = *(const unsigned*)(x + (size_t)s * 128 + lane * 2);
        }
        #pragma unroll
        for (int u = 0; u < 16; ++u) {
            if (j + u <= lim) {     // wave-uniform predicate
                a0 += __uint_as_float(v[u] << 16);
                a1 += __uint_as_float(v[u] & 0xffff0000u);
            }
        }
    }
    for (int e = s0 + 64; e < s1; ++e) {   // rare tail: deg > 64
        int s = colv[e];
        unsigned v_ = *(const unsigned*)(x + (size_t)s * 128 + lane * 2);
        a0 += __uint_as_float(v_ << 16);
        a1 += __uint_as_float(v_ & 0xffff0000u);
    }
    float inv = 1.0f / (float)(deg > 1 ? deg : 1);
    a0 *= inv;
    a1 *= inv;
    unsigned outp = ((unsigned)f2bf(a1) << 16) | (unsigned)f2bf(a0);
    *(unsigned*)(nm + (size_t)wid * 128 + lane * 2) = outp;
}

// ---------------- persistent fused GEMM ----------------
// out = act(X0*W0^T + [X1*W1^T] + bias) [*exist]
// Grid-stride over 64-node tiles. W (both phases) staged to LDS ONCE per block,
// B-fragments hoisted to registers; inner loop stages only X tiles.
// LDS: one 34.8 KB union buffer = W-staging (128x136) = X0-tile | X1-tile (64x136 each).
// raw==1: phase-0 X comes from fp32 inputs (attr/cc/bl/ex concat), converted inline.

#define LXS 8704   // shorts per 64x136 tile

__global__ __launch_bounds__(256, 3) void gemm_fused(
    const unsigned short* __restrict__ X0, const unsigned short* __restrict__ X1,
    const unsigned short* __restrict__ W0, const unsigned short* __restrict__ W1,
    const float* __restrict__ bias, const float* __restrict__ ex,
    const float* __restrict__ attr, const float* __restrict__ cc,
    const float* __restrict__ bl, const float* __restrict__ exn,
    unsigned short* __restrict__ obf, float* __restrict__ of32,
    int N, int ATTR, int relu, int nphase, int raw, int ntile) {
    __shared__ unsigned short lbuf[2 * LXS];
    int tid = threadIdx.x;
    int lane = tid & 63;
    int w = tid >> 6;
    int n_off = w * 32;
    int q = lane >> 4;
    int m16 = lane & 15;

    // ---- one-time: stage W, hoist B fragments to registers ----
    short8 bf0[2][4], bf1[2][4];
    {
        for (int i = 0; i < 8; ++i) {
            int c = tid + 256 * i;
            int rw = c >> 4, ck = c & 15;
            *(short8*)(lbuf + rw * 136 + ck * 8) = *(const short8*)(W0 + rw * 128 + ck * 8);
        }
        __syncthreads();
        #pragma unroll
        for (int nt = 0; nt < 2; ++nt)
            #pragma unroll
            for (int kk = 0; kk < 4; ++kk)
                bf0[nt][kk] = *(const short8*)(lbuf + (n_off + nt * 16 + m16) * 136 + kk * 32 + q * 8);
        __syncthreads();
        if (nphase == 2) {
            for (int i = 0; i < 8; ++i) {
                int c = tid + 256 * i;
                int rw = c >> 4, ck = c & 15;
                *(short8*)(lbuf + rw * 136 + ck * 8) = *(const short8*)(W1 + rw * 128 + ck * 8);
            }
            __syncthreads();
            #pragma unroll
            for (int nt = 0; nt < 2; ++nt)
                #pragma unroll
                for (int kk = 0; kk < 4; ++kk)
                    bf1[nt][kk] = *(const short8*)(lbuf + (n_off + nt * 16 + m16) * 136 + kk * 32 + q * 8);
            __syncthreads();
        }
    }
    float bv0 = bias[n_off + m16];
    float bv1 = bias[n_off + 16 + m16];

    for (int tile = blockIdx.x; tile < ntile; tile += gridDim.x) {
        int node0 = tile * 64;
        // ---- stage X0 tile ----
        if (raw) {
            for (int i = 0; i < 4; ++i) {
                int c = tid + 256 * i;
                int nd = c >> 4, ck = c & 15;
                int node = node0 + nd;
                short8 v = {0, 0, 0, 0, 0, 0, 0, 0};
                if (node < N) {
                    if (ck < 15) {
                        const float* p = attr + (size_t)node * ATTR + ck * 8;
                        #pragma unroll
                        for (int u = 0; u < 8; ++u) ((unsigned short*)&v)[u] = f2bf(p[u]);
                    } else {
                        #pragma unroll
                        for (int u = 0; u < 8; ++u) {
                            int col = 120 + u;
                            float f = (col < ATTR) ? attr[(size_t)node * ATTR + col]
                                    : (col == ATTR) ? cc[node]
                                    : (col == ATTR + 1) ? bl[node] : exn[node];
                            ((unsigned short*)&v)[u] = f2bf(f);
                        }
                    }
                }
                *(short8*)(lbuf + nd * 136 + ck * 8) = v;
            }
        } else {
            for (int i = 0; i < 4; ++i) {
                int c = tid + 256 * i;
                int nd = c >> 4, ck = c & 15;
                short8 v = {0, 0, 0, 0, 0, 0, 0, 0};
                if (node0 + nd < N) v = *(const short8*)(X0 + (size_t)(node0 + nd) * 128 + ck * 8);
                *(short8*)(lbuf + nd * 136 + ck * 8) = v;
            }
        }
        if (nphase == 2) {
            for (int i = 0; i < 4; ++i) {
                int c = tid + 256 * i;
                int nd = c >> 4, ck = c & 15;
                short8 v = {0, 0, 0, 0, 0, 0, 0, 0};
                if (node0 + nd < N) v = *(const short8*)(X1 + (size_t)(node0 + nd) * 128 + ck * 8);
                *(short8*)(lbuf + LXS + nd * 136 + ck * 8) = v;
            }
        }
        __syncthreads();

        // ---- MFMA ----
        floatx4 acc[4][2];
        #pragma unroll
        for (int mt = 0; mt < 4; ++mt) {
            floatx4 b40 = {bv0, bv0, bv0, bv0};
            floatx4 b41 = {bv1, bv1, bv1, bv1};
            acc[mt][0] = b40;
            acc[mt][1] = b41;
        }
        #pragma unroll
        for (int kk = 0; kk < 4; ++kk) {
            short8 a[4];
            #pragma unroll
            for (int mt = 0; mt < 4; ++mt)
                a[mt] = *(const short8*)(lbuf + (mt * 16 + m16) * 136 + kk * 32 + q * 8);
            #pragma unroll
            for (int mt = 0; mt < 4; ++mt) {
                acc[mt][0] = __builtin_amdgcn_mfma_f32_16x16x32_bf16(a[mt], bf0[0][kk], acc[mt][0], 0, 0, 0);
                acc[mt][1] = __builtin_amdgcn_mfma_f32_16x16x32_bf16(a[mt], bf0[1][kk], acc[mt][1], 0, 0, 0);
            }
        }
        if (nphase == 2) {
            #pragma unroll
            for (int kk = 0; kk < 4; ++kk) {
                short8 a[4];
                #pragma unroll
                for (int mt = 0; mt < 4; ++mt)
                    a[mt] = *(const short8*)(lbuf + LXS + (mt * 16 + m16) * 136 + kk * 32 + q * 8);
                #pragma unroll
                for (int mt = 0; mt < 4; ++mt) {
                    acc[mt][0] = __builtin_amdgcn_mfma_f32_16x16x32_bf16(a[mt], bf1[0][kk], acc[mt][0], 0, 0, 0);
                    acc[mt][1] = __builtin_amdgcn_mfma_f32_16x16x32_bf16(a[mt], bf1[1][kk], acc[mt][1], 0, 0, 0);
                }
            }
        }

        // ---- epilogue: C layout col = lane&15, row = q*4 + r ----
        #pragma unroll
        for (int mt = 0; mt < 4; ++mt) {
            int rbase = node0 + mt * 16 + q * 4;
            #pragma unroll
            for (int r = 0; r < 4; ++r) {
                int rr = rbase + r;
                if (rr >= N) continue;
                float e = ex ? ex[rr] : 1.0f;
                #pragma unroll
                for (int nt = 0; nt < 2; ++nt) {
                    float v = acc[mt][nt][r];
                    if (relu) v = fmaxf(v, 0.0f);
                    v *= e;
                    int col = n_off + nt * 16 + m16;
                    if (obf) obf[(size_t)rr * 128 + col] = f2bf(v);
                    else     of32[(size_t)rr * 128 + col] = v;
                }
            }
        }
        __syncthreads();   // lbuf reads done before next iteration restages
    }
}

// ---------------- launch ----------------

extern "C" void kernel_launch(void* const* d_in, const int* in_sizes, int n_in,
                              void* d_out, int out_size, void* d_ws, size_t ws_size,
                              hipStream_t stream) {
    const float* attr = (const float*)d_in[0];
    const float* cc   = (const float*)d_in[1];
    const float* bl   = (const float*)d_in[2];
    const float* ex   = (const float*)d_in[3];
    const float* w_in = (const float*)d_in[4];
    const float* b_in = (const float*)d_in[5];
    const float* w1s  = (const float*)d_in[6];
    const float* b1s  = (const float*)d_in[7];
    const float* w1n  = (const float*)d_in[8];
    const float* b1n  = (const float*)d_in[9];
    const float* w2s  = (const float*)d_in[10];
    const float* b2s  = (const float*)d_in[11];
    const float* w2n  = (const float*)d_in[12];
    const float* b2n  = (const float*)d_in[13];
    const int*   eidx = (const int*)d_in[14];

    int N = in_sizes[3];
    int ATTR = in_sizes[0] / N;
    int E = in_sizes[14] / 2;
    int Npad = ((N + 63) / 64) * 64;
    int nchunk = (N >> 9) + 1;
    int ntilesE = (E + BTILE - 1) / BTILE;
    int ntile = Npad / 64;
    int gblk = (ntile + 1) / 2;   // persistent gemm grid: 2 tiles/block

    char* ws = (char*)d_ws;
    size_t off = 0;
    auto alloc = [&](size_t bytes) -> char* {
        off = (off + 255) & ~(size_t)255;
        char* p = ws + off;
        off += bytes;
        return p;
    };
    unsigned short* xa = (unsigned short*)alloc((size_t)Npad * 128 * 2);  // x2
    unsigned short* xb = (unsigned short*)alloc((size_t)Npad * 128 * 2);  // x1
    unsigned short* xc = (unsigned short*)alloc((size_t)Npad * 128 * 2);  // nm1 / nm2
    int* colv = (int*)alloc((size_t)E * 4);
    unsigned* packed = (unsigned*)alloc((size_t)E * 4);
    int* rows = (int*)alloc((size_t)(N + 256) * 4);
    int* chunk_count  = (int*)alloc(128 * 4);
    int* chunk_base   = (int*)alloc(128 * 4);
    int* chunk_cursor = (int*)alloc(128 * 4);
    int* done_ctr     = (int*)alloc(4);
    unsigned short* wb = (unsigned short*)alloc((size_t)5 * 16384 * 2);
    float* biasf = (float*)alloc(3 * 128 * 4);

    prep_weights<<<(5 * 16384 + 255) / 256, 256, 0, stream>>>(
        w_in, w1s, w1n, w2s, w2n, b_in, b1s, b1n, b2s, b2n, wb, biasf,
        chunk_count, done_ctr);

    chunk_hist<<<256, 256, 0, stream>>>(eidx, chunk_count, chunk_base, chunk_cursor,
                                        done_ctr, E, 256);
    bin_pass<<<(ntilesE < 256 ? ntilesE : 256), 256, 0, stream>>>(eidx, chunk_cursor, packed, E, ntilesE);
    chunk_csr<<<nchunk, 256, 0, stream>>>(packed, chunk_base, chunk_cursor, rows, colv, N);

    // layer 0: x1 = relu(x0 @ W_in^T + b_in), x0 built inline from raw inputs
    gemm_fused<<<gblk, 256, 0, stream>>>((const unsigned short*)nullptr, (const unsigned short*)nullptr,
                                         wb, (const unsigned short*)nullptr,
                                         biasf, (const float*)nullptr,
                                         attr, cc, bl, ex,
                                         xb, (float*)nullptr, N, ATTR, 1, 1, 1, ntile);
    // nm1 = segment_mean(x1)
    agg_mean<<<(N + 3) / 4, 256, 0, stream>>>(xb, rows, colv, xc, N);
    // layer 1: x2 = relu(x1 @ W1s^T + nm1 @ W1n^T + b1s + b1n) * exist
    gemm_fused<<<gblk, 256, 0, stream>>>(xb, xc, wb + 16384, wb + 2 * 16384,
                                         biasf + 128, ex,
                                         attr, cc, bl, ex,
                                         xa, (float*)nullptr, N, ATTR, 1, 2, 0, ntile);
    // nm2 = segment_mean(x2)
    agg_mean<<<(N + 3) / 4, 256, 0, stream>>>(xa, rows, colv, xc, N);
    // layer 2: out = (x2 @ W2s^T + nm2 @ W2n^T + b2s + b2n) * exist   (fp32 out)
    gemm_fused<<<gblk, 256, 0, stream>>>(xa, xc, wb + 3 * 16384, wb + 4 * 16384,
                                         biasf + 256, ex,
                                         attr, cc, bl, ex,
                                         (unsigned short*)nullptr, (float*)d_out, N, ATTR, 0, 2, 0, ntile);
}

// Round 5
// 276.423 us; speedup vs baseline: 1.0048x; 1.0048x over previous
//
#include <hip/hip_runtime.h>
#include <hip/hip_bf16.h>

typedef __attribute__((ext_vector_type(8))) short short8;
typedef __attribute__((ext_vector_type(4))) float floatx4;

__device__ inline unsigned short f2bf(float f) {
    unsigned u = __float_as_uint(f);
    u += 0x7fffu + ((u >> 16) & 1u);   // round-to-nearest-even
    return (unsigned short)(u >> 16);
}

// ---------------- prep: weights->bf16, fused biases, zero CSR counters ----------------

__global__ void prep_weights(const float* __restrict__ w_in, const float* __restrict__ w1s,
                             const float* __restrict__ w1n, const float* __restrict__ w2s,
                             const float* __restrict__ w2n,
                             const float* __restrict__ b_in, const float* __restrict__ b1s,
                             const float* __restrict__ b1n, const float* __restrict__ b2s,
                             const float* __restrict__ b2n,
                             unsigned short* __restrict__ wb, float* __restrict__ biasf,
                             int* __restrict__ chunk_count, int* __restrict__ done_ctr) {
    int idx = blockIdx.x * 256 + threadIdx.x;
    if (idx < 5 * 16384) {
        int m = idx >> 14, j = idx & 16383;
        const float* src = (m == 0) ? w_in : (m == 1) ? w1s : (m == 2) ? w1n : (m == 3) ? w2s : w2n;
        wb[idx] = f2bf(src[j]);
    }
    if (idx < 128) {
        biasf[idx]       = b_in[idx];
        biasf[128 + idx] = b1s[idx] + b1n[idx];
        biasf[256 + idx] = b2s[idx] + b2n[idx];
    }
    if (blockIdx.x == 0) {
        if (threadIdx.x < 128) chunk_count[threadIdx.x] = 0;
        if (threadIdx.x == 128) *done_ctr = 0;
    }
}

__global__ void build_x0(const float* __restrict__ attr, const float* __restrict__ cc,
                         const float* __restrict__ bl, const float* __restrict__ ex,
                         unsigned short* __restrict__ x0, int N, int ATTR) {
    int idx = blockIdx.x * 256 + threadIdx.x;
    if (idx >= N * 128) return;
    int row = idx >> 7, col = idx & 127;
    float v;
    if (col < ATTR)            v = attr[row * ATTR + col];
    else if (col == ATTR)      v = cc[row];
    else if (col == ATTR + 1)  v = bl[row];
    else                       v = ex[row];
    x0[idx] = f2bf(v);
}

// ---------------- CSR build: binned counting sort (coalesced writes) ----------------
// chunk = 512 consecutive target nodes; NCHUNK <= 128.
// packed edge word: (chunk<<25) | (src<<9) | (tgt&511)   [requires src < 65536]

__global__ __launch_bounds__(256) void chunk_hist(const int* __restrict__ e,
                                                  int* __restrict__ chunk_count,
                                                  int* __restrict__ chunk_base,
                                                  int* __restrict__ chunk_cursor,
                                                  int* __restrict__ done_ctr,
                                                  int E, int nblocks) {
    __shared__ int h[128];
    __shared__ int lastf;
    int t = threadIdx.x;
    if (t < 128) h[t] = 0;
    __syncthreads();
    for (int i = blockIdx.x * 256 + t; i < E; i += nblocks * 256)
        atomicAdd(&h[e[E + i] >> 9], 1);
    __syncthreads();
    if (t < 128 && h[t]) atomicAdd(&chunk_count[t], h[t]);
    __threadfence();
    if (t == 0) lastf = (atomicAdd(done_ctr, 1) == nblocks - 1);
    __syncthreads();
    if (lastf) {
        // last finishing block performs the 128-wide exclusive scan
        int cv = (t < 128) ? atomicAdd(&chunk_count[t], 0) : 0;  // coherent read
        if (t < 128) h[t] = cv;
        __syncthreads();
        for (int o = 1; o < 128; o <<= 1) {
            int v = (t < 128 && t >= o) ? h[t - o] : 0;
            __syncthreads();
            if (t < 128) h[t] += v;
            __syncthreads();
        }
        if (t < 128) {
            int excl = h[t] - cv;
            chunk_base[t] = excl;
            chunk_cursor[t] = excl;
        }
    }
}

#define BTILE 4096

__global__ __launch_bounds__(256) void bin_pass(const int* __restrict__ e,
                                                int* __restrict__ chunk_cursor,
                                                unsigned* __restrict__ packed_out,
                                                int E, int ntiles) {
    __shared__ unsigned buf[BTILE];
    __shared__ unsigned sbuf[BTILE];
    __shared__ int hist[128], offs[128], gbase[128], lcur[128];
    int t = threadIdx.x;
    for (int tile = blockIdx.x; tile < ntiles; tile += gridDim.x) {
        int e0 = tile * BTILE;
        int cnt = min(BTILE, E - e0);
        if (t < 128) hist[t] = 0;
        __syncthreads();
        for (int j = t; j < cnt; j += 256) {
            unsigned src = (unsigned)e[e0 + j];
            unsigned tgt = (unsigned)e[E + e0 + j];
            unsigned c = tgt >> 9;
            buf[j] = (c << 25) | (src << 9) | (tgt & 511u);
            atomicAdd(&hist[c], 1);
        }
        __syncthreads();
        if (t < 128) offs[t] = hist[t];
        __syncthreads();
        for (int o = 1; o < 128; o <<= 1) {
            int v = (t < 128 && t >= o) ? offs[t - o] : 0;
            __syncthreads();
            if (t < 128) offs[t] += v;
            __syncthreads();
        }
        if (t < 128) {
            int excl = offs[t] - hist[t];
            offs[t] = excl;
            lcur[t] = excl;
            gbase[t] = (hist[t] > 0) ? atomicAdd(&chunk_cursor[t], hist[t]) : 0;
        }
        __syncthreads();
        for (int j = t; j < cnt; j += 256) {
            unsigned v = buf[j];
            int c = v >> 25;
            int p = atomicAdd(&lcur[c], 1);
            sbuf[p] = v;
        }
        __syncthreads();
        int wv = t >> 6, lane = t & 63;
        for (int c = wv; c < 128; c += 4) {
            int n = hist[c], lo = offs[c], gb = gbase[c];
            for (int j = lane; j < n; j += 64)
                packed_out[gb + j] = sbuf[lo + j];
        }
        __syncthreads();
    }
}

#define CSR_CAP 12288

__global__ __launch_bounds__(256) void chunk_csr(const unsigned* __restrict__ packed,
                                                 const int* __restrict__ chunk_base,
                                                 const int* __restrict__ chunk_cursor,
                                                 int* __restrict__ rows, int* __restrict__ colv,
                                                 int N) {
    __shared__ int hist[512], offs[512], lcnt[512], pp[256];
    __shared__ int sbuf[CSR_CAP];
    int c = blockIdx.x;
    int base = chunk_base[c];
    int cnt = chunk_cursor[c] - base;
    int t = threadIdx.x;
    hist[t] = 0;
    hist[t + 256] = 0;
    __syncthreads();
    for (int j = t; j < cnt; j += 256)
        atomicAdd(&hist[packed[base + j] & 511u], 1);
    __syncthreads();
    int a0 = hist[2 * t], a1 = hist[2 * t + 1];
    pp[t] = a0 + a1;
    __syncthreads();
    for (int o = 1; o < 256; o <<= 1) {
        int v = (t >= o) ? pp[t - o] : 0;
        __syncthreads();
        pp[t] += v;
        __syncthreads();
    }
    int excl = pp[t] - (a0 + a1);
    offs[2 * t] = excl;
    offs[2 * t + 1] = excl + a0;
    lcnt[2 * t] = 0;
    lcnt[2 * t + 1] = 0;
    __syncthreads();
    for (int j = t; j < 512; j += 256) {
        int node = c * 512 + j;
        if (node <= N) rows[node] = base + offs[j];
    }
    if (cnt <= CSR_CAP) {
        for (int j = t; j < cnt; j += 256) {
            unsigned v = packed[base + j];
            int node = v & 511u;
            int p = offs[node] + atomicAdd(&lcnt[node], 1);
            sbuf[p] = (v >> 9) & 0xFFFFu;
        }
        __syncthreads();
        for (int j = t; j < cnt; j += 256) colv[base + j] = sbuf[j];
    } else {
        for (int j = t; j < cnt; j += 256) {
            unsigned v = packed[base + j];
            int node = v & 511u;
            int p = offs[node] + atomicAdd(&lcnt[node], 1);
            colv[base + p] = (v >> 9) & 0xFFFFu;
        }
    }
}

// ---------------- segment mean (gather, one wave per node, 8-deep ILP) ----------------

__global__ __launch_bounds__(256) void agg_mean(const unsigned short* __restrict__ x,
                                                const int* __restrict__ rows,
                                                const int* __restrict__ colv,
                                                unsigned short* __restrict__ nm, int N) {
    int wid = (blockIdx.x * 256 + threadIdx.x) >> 6;
    int lane = threadIdx.x & 63;
    if (wid >= N) return;
    int s0 = rows[wid], s1 = rows[wid + 1];
    int deg = s1 - s0;
    int mn = deg < 64 ? deg : 64;
    int cvec = (lane < mn) ? colv[s0 + lane] : 0;
    float a0 = 0.f, a1 = 0.f;
    int lim = mn - 1;
    for (int j = 0; j < mn; j += 8) {
        unsigned v[8];
        #pragma unroll
        for (int u = 0; u < 8; ++u) {
            int idx = (j + u <= lim) ? (j + u) : lim;   // clamp: dup loads are cache hits
            int s = __shfl(cvec, idx, 64);
            v[u] = *(const unsigned*)(x + (size_t)s * 128 + lane * 2);
        }
        #pragma unroll
        for (int u = 0; u < 8; ++u) {
            if (j + u <= lim) {     // wave-uniform predicate
                a0 += __uint_as_float(v[u] << 16);
                a1 += __uint_as_float(v[u] & 0xffff0000u);
            }
        }
    }
    for (int e = s0 + 64; e < s1; ++e) {   // rare tail: deg > 64
        int s = colv[e];
        unsigned v_ = *(const unsigned*)(x + (size_t)s * 128 + lane * 2);
        a0 += __uint_as_float(v_ << 16);
        a1 += __uint_as_float(v_ & 0xffff0000u);
    }
    float inv = 1.0f / (float)(deg > 1 ? deg : 1);
    a0 *= inv;
    a1 *= inv;
    unsigned outp = ((unsigned)f2bf(a1) << 16) | (unsigned)f2bf(a0);
    *(unsigned*)(nm + (size_t)wid * 128 + lane * 2) = outp;
}

// ---------------- fused GEMM: out = act(X0*W0^T + [X1*W1^T] + bias) [*exist] ----------------
// Block: 64 nodes x 128 outputs; 4 waves, each 64x32 via 16x16x32 bf16 MFMA.
// LDS rows padded to 136 bf16 (272 B) -> conflict-free ds_read_b128.

__global__ __launch_bounds__(256, 3) void gemm_fused(
    const unsigned short* __restrict__ X0, const unsigned short* __restrict__ X1,
    const unsigned short* __restrict__ W0, const unsigned short* __restrict__ W1,
    const float* __restrict__ bias, const float* __restrict__ ex,
    unsigned short* __restrict__ obf, float* __restrict__ of32,
    int N, int relu, int nphase) {
    __shared__ unsigned short lx[64 * 136];
    __shared__ unsigned short lw[128 * 136];
    int tid = threadIdx.x;
    int lane = tid & 63;
    int w = tid >> 6;
    int node0 = blockIdx.x * 64;
    int n_off = w * 32;
    int q = lane >> 4;      // quad 0..3
    int m16 = lane & 15;

    floatx4 acc[4][2];
    for (int nt = 0; nt < 2; ++nt) {
        float bv = bias[n_off + nt * 16 + m16];
        floatx4 b4 = {bv, bv, bv, bv};
        for (int mt = 0; mt < 4; ++mt) acc[mt][nt] = b4;
    }

    for (int ph = 0; ph < nphase; ++ph) {
        const unsigned short* X = ph ? X1 : X0;
        const unsigned short* W = ph ? W1 : W0;
        // stage X tile (64 x 128)
        for (int i = 0; i < 4; ++i) {
            int c = tid + 256 * i;          // 16B chunk id, 0..1023
            int nd = c >> 4, ck = c & 15;
            short8 v = {0, 0, 0, 0, 0, 0, 0, 0};
            if (node0 + nd < N) v = *(const short8*)(X + (size_t)(node0 + nd) * 128 + ck * 8);
            *(short8*)(lx + nd * 136 + ck * 8) = v;
        }
        // stage W (128 x 128)
        for (int i = 0; i < 8; ++i) {
            int c = tid + 256 * i;          // 0..2047
            int rw = c >> 4, ck = c & 15;
            *(short8*)(lw + rw * 136 + ck * 8) = *(const short8*)(W + rw * 128 + ck * 8);
        }
        __syncthreads();
        for (int kk = 0; kk < 4; ++kk) {
            short8 a[4], b[2];
            for (int mt = 0; mt < 4; ++mt)
                a[mt] = *(const short8*)(lx + (mt * 16 + m16) * 136 + kk * 32 + q * 8);
            for (int nt = 0; nt < 2; ++nt)
                b[nt] = *(const short8*)(lw + (n_off + nt * 16 + m16) * 136 + kk * 32 + q * 8);
            for (int mt = 0; mt < 4; ++mt)
                for (int nt = 0; nt < 2; ++nt)
                    acc[mt][nt] = __builtin_amdgcn_mfma_f32_16x16x32_bf16(a[mt], b[nt], acc[mt][nt], 0, 0, 0);
        }
        __syncthreads();
    }

    // epilogue: C layout col = lane&15, row = q*4 + r
    for (int mt = 0; mt < 4; ++mt) {
        int rbase = node0 + mt * 16 + q * 4;
        for (int r = 0; r < 4; ++r) {
            int rr = rbase + r;
            if (rr >= N) continue;
            float e = ex ? ex[rr] : 1.0f;
            for (int nt = 0; nt < 2; ++nt) {
                float v = acc[mt][nt][r];
                if (relu) v = fmaxf(v, 0.0f);
                v *= e;
                int col = n_off + nt * 16 + m16;
                if (obf) obf[(size_t)rr * 128 + col] = f2bf(v);
                else     of32[(size_t)rr * 128 + col] = v;
            }
        }
    }
}

// ---------------- launch ----------------

extern "C" void kernel_launch(void* const* d_in, const int* in_sizes, int n_in,
                              void* d_out, int out_size, void* d_ws, size_t ws_size,
                              hipStream_t stream) {
    const float* attr = (const float*)d_in[0];
    const float* cc   = (const float*)d_in[1];
    const float* bl   = (const float*)d_in[2];
    const float* ex   = (const float*)d_in[3];
    const float* w_in = (const float*)d_in[4];
    const float* b_in = (const float*)d_in[5];
    const float* w1s  = (const float*)d_in[6];
    const float* b1s  = (const float*)d_in[7];
    const float* w1n  = (const float*)d_in[8];
    const float* b1n  = (const float*)d_in[9];
    const float* w2s  = (const float*)d_in[10];
    const float* b2s  = (const float*)d_in[11];
    const float* w2n  = (const float*)d_in[12];
    const float* b2n  = (const float*)d_in[13];
    const int*   eidx = (const int*)d_in[14];

    int N = in_sizes[3];
    int ATTR = in_sizes[0] / N;
    int E = in_sizes[14] / 2;
    int Npad = ((N + 63) / 64) * 64;
    int nchunk = (N >> 9) + 1;
    int ntilesE = (E + BTILE - 1) / BTILE;

    char* ws = (char*)d_ws;
    size_t off = 0;
    auto alloc = [&](size_t bytes) -> char* {
        off = (off + 255) & ~(size_t)255;
        char* p = ws + off;
        off += bytes;
        return p;
    };
    unsigned short* xa = (unsigned short*)alloc((size_t)Npad * 128 * 2);  // x0, later x2
    unsigned short* xb = (unsigned short*)alloc((size_t)Npad * 128 * 2);  // x1
    unsigned short* xc = (unsigned short*)alloc((size_t)Npad * 128 * 2);  // nm1 / nm2
    int* colv = (int*)alloc((size_t)E * 4);
    unsigned* packed = (unsigned*)alloc((size_t)E * 4);
    int* rows = (int*)alloc((size_t)(N + 256) * 4);
    int* chunk_count  = (int*)alloc(128 * 4);
    int* chunk_base   = (int*)alloc(128 * 4);
    int* chunk_cursor = (int*)alloc(128 * 4);
    int* done_ctr     = (int*)alloc(4);
    unsigned short* wb = (unsigned short*)alloc((size_t)5 * 16384 * 2);
    float* biasf = (float*)alloc(3 * 128 * 4);

    prep_weights<<<(5 * 16384 + 255) / 256, 256, 0, stream>>>(
        w_in, w1s, w1n, w2s, w2n, b_in, b1s, b1n, b2s, b2n, wb, biasf,
        chunk_count, done_ctr);
    build_x0<<<(N * 128 + 255) / 256, 256, 0, stream>>>(attr, cc, bl, ex, xa, N, ATTR);

    chunk_hist<<<256, 256, 0, stream>>>(eidx, chunk_count, chunk_base, chunk_cursor,
                                        done_ctr, E, 256);
    bin_pass<<<(ntilesE < 256 ? ntilesE : 256), 256, 0, stream>>>(eidx, chunk_cursor, packed, E, ntilesE);
    chunk_csr<<<nchunk, 256, 0, stream>>>(packed, chunk_base, chunk_cursor, rows, colv, N);

    int gblk = Npad / 64;
    // layer 0: x1 = relu(x0 @ W_in^T + b_in)
    gemm_fused<<<gblk, 256, 0, stream>>>(xa, (const unsigned short*)nullptr,
                                         wb, (const unsigned short*)nullptr,
                                         biasf, (const float*)nullptr,
                                         xb, (float*)nullptr, N, 1, 1);
    // nm1 = segment_mean(x1)
    agg_mean<<<(N + 3) / 4, 256, 0, stream>>>(xb, rows, colv, xc, N);
    // layer 1: x2 = relu(x1 @ W1s^T + nm1 @ W1n^T + b1s + b1n) * exist
    gemm_fused<<<gblk, 256, 0, stream>>>(xb, xc, wb + 16384, wb + 2 * 16384,
                                         biasf + 128, ex, xa, (float*)nullptr, N, 1, 2);
    // nm2 = segment_mean(x2)
    agg_mean<<<(N + 3) / 4, 256, 0, stream>>>(xa, rows, colv, xc, N);
    // layer 2: out = (x2 @ W2s^T + nm2 @ W2n^T + b2s + b2n) * exist   (fp32 out)
    gemm_fused<<<gblk, 256, 0, stream>>>(xa, xc, wb + 3 * 16384, wb + 4 * 16384,
                                         biasf + 256, ex, (unsigned short*)nullptr,
                                         (float*)d_out, N, 0, 2);
}